// Round 4
// baseline (104.267 us; speedup 1.0000x reference)
//
#include <hip/hip_runtime.h>
#include <hip/hip_bf16.h>

// EDMultiheadRetention: S=128, D=4096, H=32, hd=128
// Pipeline: prep (cast x + kvsT) -> gemm_split (KS=4 partials, A direct-from-L2,
//           B through swizzled LDS) -> reduce (decay+layouts) -> heads

typedef __bf16 bf16x8 __attribute__((ext_vector_type(8)));
typedef float f32x4 __attribute__((ext_vector_type(4)));

static __device__ __forceinline__ f32x4 mfma_bf16(bf16x8 a, bf16x8 b, f32x4 c) {
  return __builtin_amdgcn_mfma_f32_16x16x32_bf16(a, b, c, 0, 0, 0);
}

static __device__ __forceinline__ bf16x8 cvt8(float4 lo, float4 hi) {
  return (bf16x8){(__bf16)lo.x, (__bf16)lo.y, (__bf16)lo.z, (__bf16)lo.w,
                  (__bf16)hi.x, (__bf16)hi.y, (__bf16)hi.z, (__bf16)hi.w};
}

// ---------------- kernel 1: cast x -> bf16 (blocks 0..255), kvsT prep (256..383)
__global__ __launch_bounds__(256) void prep_kernel(const float* __restrict__ x,
                                                   __bf16* __restrict__ xb,
                                                   const float* __restrict__ kvs,
                                                   const float* __restrict__ alpha,
                                                   __bf16* __restrict__ kvsT) {
  __shared__ float lds[32][129];
  const int tid = threadIdx.x;
  if (blockIdx.x < 256) {
    const int i = (blockIdx.x * 256 + tid) * 8;
    float4 a = *(const float4*)(x + i);
    float4 b = *(const float4*)(x + i + 4);
    *(bf16x8*)(xb + i) = cvt8(a, b);
    return;
  }
  const int bid = blockIdx.x - 256;
  const int h = bid >> 2, dq = bid & 3;
  const int j = tid & 127, dg = tid >> 7;
  const int d0 = dq * 32;
#pragma unroll
  for (int i = 0; i < 16; ++i) {
    const int dloc = dg * 16 + i;
    const int d = d0 + dloc;
    const float dS = exp2f(128.f * log2f(alpha[h * 128 + d]));
    lds[dloc][j] = kvs[(size_t)h * 16384 + d * 128 + j] * dS;
  }
  __syncthreads();
  const int jj = tid >> 1, dh = tid & 1;
  bf16x8 a0, a1;
#pragma unroll
  for (int i = 0; i < 8; ++i) a0[i] = (__bf16)lds[dh * 16 + i][jj];
#pragma unroll
  for (int i = 0; i < 8; ++i) a1[i] = (__bf16)lds[dh * 16 + 8 + i][jj];
  *(bf16x8*)(kvsT + (size_t)h * 16384 + jj * 128 + d0 + dh * 16) = a0;
  *(bf16x8*)(kvsT + (size_t)h * 16384 + jj * 128 + d0 + dh * 16 + 8) = a1;
}

// ---------------- kernel 2: split-K GEMM: P[ks][s][n] = x @ W^T (partial) ---
// 256 thr (4 waves 2x2), tile M=128 x N=64, BK=64.
// A fragments load DIRECT from global (x is L2-hot; 16 full 64B lines per b128).
// B (=W rows) reg-staged f32->bf16 into XOR-swizzled double-buffered LDS (16 KB).
__global__ __launch_bounds__(256, 4) void gemm_split_kernel(const __bf16* __restrict__ xb,
                                                            const float* __restrict__ W,
                                                            float* __restrict__ P,
                                                            int kc_len) {
  __shared__ __bf16 Bld[2][64 * 64];

  const int tid = threadIdx.x;
  const int wid = tid >> 6, lane = tid & 63;
  const int r0 = lane & 15, l4 = lane >> 4, rr = l4 << 2;
  const int nt = blockIdx.x % 192, ks = blockIdx.x / 192;
  const int n0 = nt * 64;
  const int kb0 = ks * kc_len;
  const int wm = wid & 1, wn = wid >> 1;

  // B staging: 2 units/thread; unit u -> (row=u>>3, phys chunk p=u&7),
  // source logical chunk g = p ^ (row&7)
  int b_elem[2];
  const float* wp[2];
#pragma unroll
  for (int i = 0; i < 2; ++i) {
    const int u = i * 256 + tid;
    const int row = u >> 3;
    const int p = u & 7;
    const int koff = (p ^ (row & 7)) << 3;
    b_elem[i] = row * 64 + p * 8;
    wp[i] = W + (size_t)(n0 + row) * 4096 + kb0 + koff;
  }

  // B fragment read offsets (elements), logical chunk c = kh*4+l4, phys = c^(row&7)
  int b_off[2][2];
#pragma unroll
  for (int nf = 0; nf < 2; ++nf)
#pragma unroll
    for (int kh = 0; kh < 2; ++kh) {
      const int row = wn * 32 + nf * 16 + r0;
      const int p = (kh * 4 + l4) ^ (row & 7);
      b_off[nf][kh] = row * 64 + p * 8;
    }

  // A direct-global fragment base pointers
  const __bf16* a_ptr[4];
#pragma unroll
  for (int mf = 0; mf < 4; ++mf)
    a_ptr[mf] = xb + (size_t)(wm * 64 + mf * 16 + r0) * 4096 + kb0 + l4 * 8;

  f32x4 acc[4][2];
#pragma unroll
  for (int mf = 0; mf < 4; ++mf)
#pragma unroll
    for (int nf = 0; nf < 2; ++nf) acc[mf][nf] = (f32x4){0.f, 0.f, 0.f, 0.f};

  // prologue: stage W tile 0 into buf 0
  {
#pragma unroll
    for (int i = 0; i < 2; ++i) {
      float4 lo = *(const float4*)(wp[i]);
      float4 hi = *(const float4*)(wp[i] + 4);
      *(bf16x8*)(&Bld[0][b_elem[i]]) = cvt8(lo, hi);
    }
  }
  __syncthreads();

  const int iters = kc_len >> 6;
  for (int kt = 0; kt < iters; ++kt) {
    const int cur = kt & 1, nxt = cur ^ 1;
    const bool has_next = (kt + 1 < iters);
    float4 wlo[2], whi[2];
    if (has_next) {
      const int kb = (kt + 1) * 64;
#pragma unroll
      for (int i = 0; i < 2; ++i) {
        wlo[i] = *(const float4*)(wp[i] + kb);
        whi[i] = *(const float4*)(wp[i] + kb + 4);
      }
    }

    bf16x8 af[4][2], bfr[2][2];
#pragma unroll
    for (int kh = 0; kh < 2; ++kh)
#pragma unroll
      for (int nf = 0; nf < 2; ++nf) bfr[nf][kh] = *(const bf16x8*)(&Bld[cur][b_off[nf][kh]]);
#pragma unroll
    for (int mf = 0; mf < 4; ++mf)
#pragma unroll
      for (int kh = 0; kh < 2; ++kh)
        af[mf][kh] = *(const bf16x8*)(a_ptr[mf] + kt * 64 + kh * 32);

#pragma unroll
    for (int kh = 0; kh < 2; ++kh)
#pragma unroll
      for (int mf = 0; mf < 4; ++mf)
#pragma unroll
        for (int nf = 0; nf < 2; ++nf)
          acc[mf][nf] = mfma_bf16(af[mf][kh], bfr[nf][kh], acc[mf][nf]);

    if (has_next) {
#pragma unroll
      for (int i = 0; i < 2; ++i) *(bf16x8*)(&Bld[nxt][b_elem[i]]) = cvt8(wlo[i], whi[i]);
    }
    __syncthreads();
  }

  // epilogue: write partials P[ks][s][n]
#pragma unroll
  for (int mf = 0; mf < 4; ++mf)
#pragma unroll
    for (int nf = 0; nf < 2; ++nf)
#pragma unroll
      for (int r = 0; r < 4; ++r) {
        const int s = wm * 64 + mf * 16 + rr + r;
        const int n = n0 + wn * 32 + nf * 16 + r0;
        P[(size_t)ks * 1572864 + (size_t)s * 12288 + n] = acc[mf][nf][r];
      }
}

// ---------------- kernel 3: reduce partials, apply decay, emit bf16 layouts
// qd/kd [h][s][d], kdT/vT [h][d][s]
__global__ __launch_bounds__(256) void reduce_kernel(const float* __restrict__ P,
                                                     const float* __restrict__ alpha,
                                                     __bf16* __restrict__ qd,
                                                     __bf16* __restrict__ kd,
                                                     __bf16* __restrict__ kdT,
                                                     __bf16* __restrict__ vT, int KS) {
  __shared__ float lds[32][129];
  const int bid = blockIdx.x;
  const int which = bid >> 7;  // 0=q 1=k 2=v
  const int rem = bid & 127;
  const int h = rem >> 2, sq = rem & 3;
  const int tid = threadIdx.x;
  const int d = tid & 127, sg = tid >> 7;
  const int n = which * 4096 + h * 128 + d;
  const int s0 = sq * 32;
  const float la = log2f(alpha[h * 128 + d]);

#pragma unroll 4
  for (int si = 0; si < 16; ++si) {
    const int s = s0 + sg * 16 + si;
    float val = 0.f;
#pragma unroll
    for (int ksi = 0; ksi < 4; ++ksi)
      if (ksi < KS) val += P[(size_t)ksi * 1572864 + (size_t)s * 12288 + n];
    if (which == 0)
      val *= exp2f((float)(s - 127) * la - 6.0f);
    else if (which == 1)
      val *= exp2f((float)(127 - s) * la - 6.0f);
    lds[sg * 16 + si][d] = val;
    if (which == 0)
      qd[(size_t)h * 16384 + s * 128 + d] = (__bf16)val;
    else if (which == 1)
      kd[(size_t)h * 16384 + s * 128 + d] = (__bf16)val;
  }
  if (which == 0) return;
  __syncthreads();
  __bf16* outT = (which == 1 ? kdT : vT) + (size_t)h * 16384;
  const int dd = tid >> 1, sh = tid & 1;
  bf16x8 v0, v1;
#pragma unroll
  for (int i = 0; i < 8; ++i) v0[i] = (__bf16)lds[sh * 16 + i][dd];
#pragma unroll
  for (int i = 0; i < 8; ++i) v1[i] = (__bf16)lds[sh * 16 + 8 + i][dd];
  *(bf16x8*)(outT + dd * 128 + s0 + sh * 16) = v0;
  *(bf16x8*)(outT + dd * 128 + s0 + sh * 16 + 8) = v1;
}

// ---------------- kernel 4: per-head retention (all contiguous bf16 loads) --
// bid<128: out rows; bid>=128: new_kvs rows. 128 threads (2 waves).
__global__ __launch_bounds__(128) void heads_kernel(const __bf16* __restrict__ qd,
                                                    const __bf16* __restrict__ kd,
                                                    const __bf16* __restrict__ kdT,
                                                    const __bf16* __restrict__ vT,
                                                    const __bf16* __restrict__ kvsT,
                                                    const float* __restrict__ kvs,
                                                    const float* __restrict__ alpha,
                                                    float* __restrict__ out) {
  const int bid = blockIdx.x;
  const int tid = threadIdx.x;
  const int wid = tid >> 6, lane = tid & 63;
  const int r0 = lane & 15, l4 = lane >> 4;
  const int g8 = l4 << 3, rr = l4 << 2;

  if (bid < 128) {
    const int h = bid >> 2, w = bid & 3;
    const int m_base = w * 32;
    __shared__ __bf16 attn_s[32][136];
    const __bf16* qh = qd + (size_t)h * 16384;
    const __bf16* kh = kd + (size_t)h * 16384;

    f32x4 acc[2][4];
#pragma unroll
    for (int mf = 0; mf < 2; ++mf)
#pragma unroll
      for (int nf = 0; nf < 4; ++nf) acc[mf][nf] = (f32x4){0.f, 0.f, 0.f, 0.f};

    // phase 1: attn cols wid*64..+64
#pragma unroll
    for (int k0 = 0; k0 < 128; k0 += 32) {
      const int kk = k0 + g8;
      bf16x8 a[2];
#pragma unroll
      for (int mf = 0; mf < 2; ++mf)
        a[mf] = *(const bf16x8*)(qh + (m_base + mf * 16 + r0) * 128 + kk);
#pragma unroll
      for (int nf = 0; nf < 4; ++nf) {
        const int jn = wid * 64 + nf * 16 + r0;
        bf16x8 b = *(const bf16x8*)(kh + jn * 128 + kk);
#pragma unroll
        for (int mf = 0; mf < 2; ++mf) acc[mf][nf] = mfma_bf16(a[mf], b, acc[mf][nf]);
      }
    }
#pragma unroll
    for (int mf = 0; mf < 2; ++mf)
#pragma unroll
      for (int nf = 0; nf < 4; ++nf)
#pragma unroll
        for (int r = 0; r < 4; ++r) {
          const int i = m_base + mf * 16 + rr + r;
          const int j = wid * 64 + nf * 16 + r0;
          attn_s[mf * 16 + rr + r][j] = (__bf16)((j <= i) ? acc[mf][nf][r] : 0.f);
        }
    __syncthreads();

    // phase 2: out = gelu(attn @ v + q @ kvsT), d2 in wid*64..+64
#pragma unroll
    for (int mf = 0; mf < 2; ++mf)
#pragma unroll
      for (int nf = 0; nf < 4; ++nf) acc[mf][nf] = (f32x4){0.f, 0.f, 0.f, 0.f};
    const __bf16* vTh = vT + (size_t)h * 16384;
    const __bf16* kvsTh = kvsT + (size_t)h * 16384;
#pragma unroll
    for (int k0 = 0; k0 < 128; k0 += 32) {
      const int kk = k0 + g8;
      bf16x8 a[2];
#pragma unroll
      for (int mf = 0; mf < 2; ++mf)
        a[mf] = *(const bf16x8*)(&attn_s[mf * 16 + r0][kk]);
#pragma unroll
      for (int nf = 0; nf < 4; ++nf) {
        const int d2 = wid * 64 + nf * 16 + r0;
        bf16x8 b = *(const bf16x8*)(vTh + d2 * 128 + kk);
#pragma unroll
        for (int mf = 0; mf < 2; ++mf) acc[mf][nf] = mfma_bf16(a[mf], b, acc[mf][nf]);
      }
    }
#pragma unroll
    for (int k0 = 0; k0 < 128; k0 += 32) {
      const int kk = k0 + g8;
      bf16x8 a[2];
#pragma unroll
      for (int mf = 0; mf < 2; ++mf)
        a[mf] = *(const bf16x8*)(qh + (m_base + mf * 16 + r0) * 128 + kk);
#pragma unroll
      for (int nf = 0; nf < 4; ++nf) {
        const int d2 = wid * 64 + nf * 16 + r0;
        bf16x8 b = *(const bf16x8*)(kvsTh + d2 * 128 + kk);
#pragma unroll
        for (int mf = 0; mf < 2; ++mf) acc[mf][nf] = mfma_bf16(a[mf], b, acc[mf][nf]);
      }
    }
#pragma unroll
    for (int mf = 0; mf < 2; ++mf)
#pragma unroll
      for (int nf = 0; nf < 4; ++nf)
#pragma unroll
        for (int r = 0; r < 4; ++r) {
          const int s = m_base + mf * 16 + rr + r;
          const int d2 = wid * 64 + nf * 16 + r0;
          const float y = acc[mf][nf][r];
          const float u = 0.7978845608028654f * (y + 0.044715f * y * y * y);
          out[(size_t)s * 4096 + h * 128 + d2] = 0.5f * y * (1.f + tanhf(u));
        }
  } else {
    const int b2 = bid - 128;
    const int h = b2 >> 2, w = b2 & 3;
    const int m_base = w * 32;
    const __bf16* kTh = kdT + (size_t)h * 16384;
    const __bf16* vTh = vT + (size_t)h * 16384;

    f32x4 acc[2][4];
#pragma unroll
    for (int mf = 0; mf < 2; ++mf)
#pragma unroll
      for (int nf = 0; nf < 4; ++nf) acc[mf][nf] = (f32x4){0.f, 0.f, 0.f, 0.f};
#pragma unroll
    for (int k0 = 0; k0 < 128; k0 += 32) {
      const int kk = k0 + g8;
      bf16x8 a[2];
#pragma unroll
      for (int mf = 0; mf < 2; ++mf)
        a[mf] = *(const bf16x8*)(kTh + (m_base + mf * 16 + r0) * 128 + kk);
#pragma unroll
      for (int nf = 0; nf < 4; ++nf) {
        const int j = wid * 64 + nf * 16 + r0;
        bf16x8 b = *(const bf16x8*)(vTh + j * 128 + kk);
#pragma unroll
        for (int mf = 0; mf < 2; ++mf) acc[mf][nf] = mfma_bf16(a[mf], b, acc[mf][nf]);
      }
    }
#pragma unroll
    for (int mf = 0; mf < 2; ++mf)
#pragma unroll
      for (int nf = 0; nf < 4; ++nf)
#pragma unroll
        for (int r = 0; r < 4; ++r) {
          const int i = m_base + mf * 16 + rr + r;
          const int j = wid * 64 + nf * 16 + r0;
          const float dSi = exp2f(128.f * log2f(alpha[h * 128 + i]));
          const float val = acc[mf][nf][r] + kvs[(size_t)h * 16384 + i * 128 + j] * dSi;
          out[524288 + (size_t)h * 16384 + i * 128 + j] = val;
        }
  }
}

extern "C" void kernel_launch(void* const* d_in, const int* in_sizes, int n_in,
                              void* d_out, int out_size, void* d_ws, size_t ws_size,
                              hipStream_t stream) {
  const float* x = (const float*)d_in[0];      // (128, 4096)
  const float* W = (const float*)d_in[1];      // (12288, 4096)
  const float* alpha = (const float*)d_in[2];  // (32, 128)
  const float* kvs = (const float*)d_in[3];    // (32, 128, 128)
  float* out = (float*)d_out;

  char* ws = (char*)d_ws;
  __bf16* xb = (__bf16*)ws;                      // 1 MB
  __bf16* qd = (__bf16*)(ws + (1u << 20));       // 1 MB each
  __bf16* kd = (__bf16*)(ws + 2u * (1u << 20));
  __bf16* kdT = (__bf16*)(ws + 3u * (1u << 20));
  __bf16* vT = (__bf16*)(ws + 4u * (1u << 20));
  __bf16* kvsT = (__bf16*)(ws + 5u * (1u << 20));
  float* P = (float*)(ws + 6u * (1u << 20));     // KS * 6,291,456 B

  const size_t pbytes = ws_size > 6u * (1u << 20) ? ws_size - 6u * (1u << 20) : 0;
  int KS = 1;
  while (KS < 4 && (size_t)(KS * 2) * 6291456ull <= pbytes) KS *= 2;
  const int kc_len = 4096 / KS;

  prep_kernel<<<384, 256, 0, stream>>>(x, xb, kvs, alpha, kvsT);
  gemm_split_kernel<<<192 * KS, 256, 0, stream>>>(xb, W, P, kc_len);
  reduce_kernel<<<384, 256, 0, stream>>>(P, alpha, qd, kd, kdT, vT, KS);
  heads_kernel<<<256, 128, 0, stream>>>(qd, kd, kdT, vT, kvsT, kvs, alpha, out);
}

// Round 5
// 98.585 us; speedup vs baseline: 1.0576x; 1.0576x over previous
//
#include <hip/hip_runtime.h>
#include <hip/hip_bf16.h>

// EDMultiheadRetention: S=128, D=4096, H=32, hd=128
// Pipeline: prep (cast x + kvsT) -> gemm_split (KS=4 partials; A direct-from-L2
//           with 1-iter register prefetch; B via swizzled LDS dbuf) -> reduce -> heads

typedef __bf16 bf16x8 __attribute__((ext_vector_type(8)));
typedef float f32x4 __attribute__((ext_vector_type(4)));

static __device__ __forceinline__ f32x4 mfma_bf16(bf16x8 a, bf16x8 b, f32x4 c) {
  return __builtin_amdgcn_mfma_f32_16x16x32_bf16(a, b, c, 0, 0, 0);
}

static __device__ __forceinline__ bf16x8 cvt8(float4 lo, float4 hi) {
  return (bf16x8){(__bf16)lo.x, (__bf16)lo.y, (__bf16)lo.z, (__bf16)lo.w,
                  (__bf16)hi.x, (__bf16)hi.y, (__bf16)hi.z, (__bf16)hi.w};
}

// ---------------- kernel 1: cast x -> bf16 (blocks 0..255), kvsT prep (256..383)
__global__ __launch_bounds__(256) void prep_kernel(const float* __restrict__ x,
                                                   __bf16* __restrict__ xb,
                                                   const float* __restrict__ kvs,
                                                   const float* __restrict__ alpha,
                                                   __bf16* __restrict__ kvsT) {
  __shared__ float lds[32][129];
  const int tid = threadIdx.x;
  if (blockIdx.x < 256) {
    const int i = (blockIdx.x * 256 + tid) * 8;
    float4 a = *(const float4*)(x + i);
    float4 b = *(const float4*)(x + i + 4);
    *(bf16x8*)(xb + i) = cvt8(a, b);
    return;
  }
  const int bid = blockIdx.x - 256;
  const int h = bid >> 2, dq = bid & 3;
  const int j = tid & 127, dg = tid >> 7;
  const int d0 = dq * 32;
#pragma unroll
  for (int i = 0; i < 16; ++i) {
    const int dloc = dg * 16 + i;
    const int d = d0 + dloc;
    const float dS = exp2f(128.f * log2f(alpha[h * 128 + d]));
    lds[dloc][j] = kvs[(size_t)h * 16384 + d * 128 + j] * dS;
  }
  __syncthreads();
  const int jj = tid >> 1, dh = tid & 1;
  bf16x8 a0, a1;
#pragma unroll
  for (int i = 0; i < 8; ++i) a0[i] = (__bf16)lds[dh * 16 + i][jj];
#pragma unroll
  for (int i = 0; i < 8; ++i) a1[i] = (__bf16)lds[dh * 16 + 8 + i][jj];
  *(bf16x8*)(kvsT + (size_t)h * 16384 + jj * 128 + d0 + dh * 16) = a0;
  *(bf16x8*)(kvsT + (size_t)h * 16384 + jj * 128 + d0 + dh * 16 + 8) = a1;
}

// ---------------- kernel 2: split-K GEMM: P[ks][s][n] = x @ W^T (partial) ---
// 256 thr (4 waves 2x2), tile M=128 x N=64, BK=64.
// A fragments: direct global loads, double-buffered in REGISTERS one K-tile ahead.
// B (=W rows): reg-staged f32->bf16 into XOR-swizzled double-buffered LDS (16 KB).
__global__ __launch_bounds__(256, 3) void gemm_split_kernel(const __bf16* __restrict__ xb,
                                                            const float* __restrict__ W,
                                                            float* __restrict__ P,
                                                            int kc_len) {
  __shared__ __bf16 Bld[2][64 * 64];

  const int tid = threadIdx.x;
  const int wid = tid >> 6, lane = tid & 63;
  const int r0 = lane & 15, l4 = lane >> 4, rr = l4 << 2;
  const int nt = blockIdx.x % 192, ks = blockIdx.x / 192;
  const int n0 = nt * 64;
  const int kb0 = ks * kc_len;
  const int wm = wid & 1, wn = wid >> 1;

  // B staging: 2 units/thread; unit u -> (row=u>>3, phys chunk p=u&7),
  // source logical chunk g = p ^ (row&7). ds_write addresses are tid-contiguous.
  int b_elem[2];
  const float* wp[2];
#pragma unroll
  for (int i = 0; i < 2; ++i) {
    const int u = i * 256 + tid;
    const int row = u >> 3;
    const int p = u & 7;
    const int koff = (p ^ (row & 7)) << 3;
    b_elem[i] = row * 64 + p * 8;
    wp[i] = W + (size_t)(n0 + row) * 4096 + kb0 + koff;
  }

  // B fragment read offsets: logical chunk c = kh*4+l4, phys = c^(row&7)
  int b_off[2][2];
#pragma unroll
  for (int nf = 0; nf < 2; ++nf)
#pragma unroll
    for (int kh = 0; kh < 2; ++kh) {
      const int row = wn * 32 + nf * 16 + r0;
      const int p = (kh * 4 + l4) ^ (row & 7);
      b_off[nf][kh] = row * 64 + p * 8;
    }

  // A direct-global fragment base pointers
  const __bf16* a_ptr[4];
#pragma unroll
  for (int mf = 0; mf < 4; ++mf)
    a_ptr[mf] = xb + (size_t)(wm * 64 + mf * 16 + r0) * 4096 + kb0 + l4 * 8;

  f32x4 acc[4][2];
#pragma unroll
  for (int mf = 0; mf < 4; ++mf)
#pragma unroll
    for (int nf = 0; nf < 2; ++nf) acc[mf][nf] = (f32x4){0.f, 0.f, 0.f, 0.f};

  bf16x8 afA[4][2], afB[4][2];

  // prologue: stage W tile 0 -> Bld[0]; A tile 0 -> afA
  {
#pragma unroll
    for (int i = 0; i < 2; ++i) {
      float4 lo = *(const float4*)(wp[i]);
      float4 hi = *(const float4*)(wp[i] + 4);
      *(bf16x8*)(&Bld[0][b_elem[i]]) = cvt8(lo, hi);
    }
#pragma unroll
    for (int mf = 0; mf < 4; ++mf)
#pragma unroll
      for (int kh = 0; kh < 2; ++kh)
        afA[mf][kh] = *(const bf16x8*)(a_ptr[mf] + kh * 32);
  }
  __syncthreads();

  const int iters = kc_len >> 6;  // always even (16 at KS=4)
  for (int kt = 0; kt < iters; kt += 2) {
    // ---- even sub-iter: compute kt (afA, Bld[0]); prefetch kt+1 (always exists)
    {
      const int kb = (kt + 1) * 64;
      float4 wlo[2], whi[2];
#pragma unroll
      for (int i = 0; i < 2; ++i) {
        wlo[i] = *(const float4*)(wp[i] + kb);
        whi[i] = *(const float4*)(wp[i] + kb + 4);
      }
#pragma unroll
      for (int mf = 0; mf < 4; ++mf)
#pragma unroll
        for (int kh = 0; kh < 2; ++kh)
          afB[mf][kh] = *(const bf16x8*)(a_ptr[mf] + kb + kh * 32);

      bf16x8 bfr[2][2];
#pragma unroll
      for (int kh = 0; kh < 2; ++kh)
#pragma unroll
        for (int nf = 0; nf < 2; ++nf) bfr[nf][kh] = *(const bf16x8*)(&Bld[0][b_off[nf][kh]]);
#pragma unroll
      for (int kh = 0; kh < 2; ++kh)
#pragma unroll
        for (int mf = 0; mf < 4; ++mf)
#pragma unroll
          for (int nf = 0; nf < 2; ++nf)
            acc[mf][nf] = mfma_bf16(afA[mf][kh], bfr[nf][kh], acc[mf][nf]);

#pragma unroll
      for (int i = 0; i < 2; ++i) *(bf16x8*)(&Bld[1][b_elem[i]]) = cvt8(wlo[i], whi[i]);
      __syncthreads();
    }
    // ---- odd sub-iter: compute kt+1 (afB, Bld[1]); prefetch kt+2 if it exists
    {
      const bool hn = (kt + 2 < iters);
      float4 wlo[2], whi[2];
      if (hn) {
        const int kb = (kt + 2) * 64;
#pragma unroll
        for (int i = 0; i < 2; ++i) {
          wlo[i] = *(const float4*)(wp[i] + kb);
          whi[i] = *(const float4*)(wp[i] + kb + 4);
        }
#pragma unroll
        for (int mf = 0; mf < 4; ++mf)
#pragma unroll
          for (int kh = 0; kh < 2; ++kh)
            afA[mf][kh] = *(const bf16x8*)(a_ptr[mf] + kb + kh * 32);
      }

      bf16x8 bfr[2][2];
#pragma unroll
      for (int kh = 0; kh < 2; ++kh)
#pragma unroll
        for (int nf = 0; nf < 2; ++nf) bfr[nf][kh] = *(const bf16x8*)(&Bld[1][b_off[nf][kh]]);
#pragma unroll
      for (int kh = 0; kh < 2; ++kh)
#pragma unroll
        for (int mf = 0; mf < 4; ++mf)
#pragma unroll
          for (int nf = 0; nf < 2; ++nf)
            acc[mf][nf] = mfma_bf16(afB[mf][kh], bfr[nf][kh], acc[mf][nf]);

      if (hn) {
#pragma unroll
        for (int i = 0; i < 2; ++i) *(bf16x8*)(&Bld[0][b_elem[i]]) = cvt8(wlo[i], whi[i]);
      }
      __syncthreads();
    }
  }

  // epilogue: write partials P[ks][s][n]
#pragma unroll
  for (int mf = 0; mf < 4; ++mf)
#pragma unroll
    for (int nf = 0; nf < 2; ++nf)
#pragma unroll
      for (int r = 0; r < 4; ++r) {
        const int s = wm * 64 + mf * 16 + rr + r;
        const int n = n0 + wn * 32 + nf * 16 + r0;
        P[(size_t)ks * 1572864 + (size_t)s * 12288 + n] = acc[mf][nf][r];
      }
}

// ---------------- kernel 3: reduce partials, apply decay, emit bf16 layouts
// qd/kd [h][s][d], kdT/vT [h][d][s]
__global__ __launch_bounds__(256) void reduce_kernel(const float* __restrict__ P,
                                                     const float* __restrict__ alpha,
                                                     __bf16* __restrict__ qd,
                                                     __bf16* __restrict__ kd,
                                                     __bf16* __restrict__ kdT,
                                                     __bf16* __restrict__ vT, int KS) {
  __shared__ float lds[32][129];
  const int bid = blockIdx.x;
  const int which = bid >> 7;  // 0=q 1=k 2=v
  const int rem = bid & 127;
  const int h = rem >> 2, sq = rem & 3;
  const int tid = threadIdx.x;
  const int d = tid & 127, sg = tid >> 7;
  const int n = which * 4096 + h * 128 + d;
  const int s0 = sq * 32;
  const float la = log2f(alpha[h * 128 + d]);

#pragma unroll 4
  for (int si = 0; si < 16; ++si) {
    const int s = s0 + sg * 16 + si;
    float val = 0.f;
#pragma unroll
    for (int ksi = 0; ksi < 4; ++ksi)
      if (ksi < KS) val += P[(size_t)ksi * 1572864 + (size_t)s * 12288 + n];
    if (which == 0)
      val *= exp2f((float)(s - 127) * la - 6.0f);
    else if (which == 1)
      val *= exp2f((float)(127 - s) * la - 6.0f);
    lds[sg * 16 + si][d] = val;
    if (which == 0)
      qd[(size_t)h * 16384 + s * 128 + d] = (__bf16)val;
    else if (which == 1)
      kd[(size_t)h * 16384 + s * 128 + d] = (__bf16)val;
  }
  if (which == 0) return;
  __syncthreads();
  __bf16* outT = (which == 1 ? kdT : vT) + (size_t)h * 16384;
  const int dd = tid >> 1, sh = tid & 1;
  bf16x8 v0, v1;
#pragma unroll
  for (int i = 0; i < 8; ++i) v0[i] = (__bf16)lds[sh * 16 + i][dd];
#pragma unroll
  for (int i = 0; i < 8; ++i) v1[i] = (__bf16)lds[sh * 16 + 8 + i][dd];
  *(bf16x8*)(outT + dd * 128 + s0 + sh * 16) = v0;
  *(bf16x8*)(outT + dd * 128 + s0 + sh * 16 + 8) = v1;
}

// ---------------- kernel 4: per-head retention (all contiguous bf16 loads) --
// bid<128: out rows; bid>=128: new_kvs rows. 128 threads (2 waves).
__global__ __launch_bounds__(128) void heads_kernel(const __bf16* __restrict__ qd,
                                                    const __bf16* __restrict__ kd,
                                                    const __bf16* __restrict__ kdT,
                                                    const __bf16* __restrict__ vT,
                                                    const __bf16* __restrict__ kvsT,
                                                    const float* __restrict__ kvs,
                                                    const float* __restrict__ alpha,
                                                    float* __restrict__ out) {
  const int bid = blockIdx.x;
  const int tid = threadIdx.x;
  const int wid = tid >> 6, lane = tid & 63;
  const int r0 = lane & 15, l4 = lane >> 4;
  const int g8 = l4 << 3, rr = l4 << 2;

  if (bid < 128) {
    const int h = bid >> 2, w = bid & 3;
    const int m_base = w * 32;
    __shared__ __bf16 attn_s[32][136];
    const __bf16* qh = qd + (size_t)h * 16384;
    const __bf16* kh = kd + (size_t)h * 16384;

    f32x4 acc[2][4];
#pragma unroll
    for (int mf = 0; mf < 2; ++mf)
#pragma unroll
      for (int nf = 0; nf < 4; ++nf) acc[mf][nf] = (f32x4){0.f, 0.f, 0.f, 0.f};

    // phase 1: attn cols wid*64..+64
#pragma unroll
    for (int k0 = 0; k0 < 128; k0 += 32) {
      const int kk = k0 + g8;
      bf16x8 a[2];
#pragma unroll
      for (int mf = 0; mf < 2; ++mf)
        a[mf] = *(const bf16x8*)(qh + (m_base + mf * 16 + r0) * 128 + kk);
#pragma unroll
      for (int nf = 0; nf < 4; ++nf) {
        const int jn = wid * 64 + nf * 16 + r0;
        bf16x8 b = *(const bf16x8*)(kh + jn * 128 + kk);
#pragma unroll
        for (int mf = 0; mf < 2; ++mf) acc[mf][nf] = mfma_bf16(a[mf], b, acc[mf][nf]);
      }
    }
#pragma unroll
    for (int mf = 0; mf < 2; ++mf)
#pragma unroll
      for (int nf = 0; nf < 4; ++nf)
#pragma unroll
        for (int r = 0; r < 4; ++r) {
          const int i = m_base + mf * 16 + rr + r;
          const int j = wid * 64 + nf * 16 + r0;
          attn_s[mf * 16 + rr + r][j] = (__bf16)((j <= i) ? acc[mf][nf][r] : 0.f);
        }
    __syncthreads();

    // phase 2: out = gelu(attn @ v + q @ kvsT), d2 in wid*64..+64
#pragma unroll
    for (int mf = 0; mf < 2; ++mf)
#pragma unroll
      for (int nf = 0; nf < 4; ++nf) acc[mf][nf] = (f32x4){0.f, 0.f, 0.f, 0.f};
    const __bf16* vTh = vT + (size_t)h * 16384;
    const __bf16* kvsTh = kvsT + (size_t)h * 16384;
#pragma unroll
    for (int k0 = 0; k0 < 128; k0 += 32) {
      const int kk = k0 + g8;
      bf16x8 a[2];
#pragma unroll
      for (int mf = 0; mf < 2; ++mf)
        a[mf] = *(const bf16x8*)(&attn_s[mf * 16 + r0][kk]);
#pragma unroll
      for (int nf = 0; nf < 4; ++nf) {
        const int d2 = wid * 64 + nf * 16 + r0;
        bf16x8 b = *(const bf16x8*)(vTh + d2 * 128 + kk);
#pragma unroll
        for (int mf = 0; mf < 2; ++mf) acc[mf][nf] = mfma_bf16(a[mf], b, acc[mf][nf]);
      }
    }
#pragma unroll
    for (int k0 = 0; k0 < 128; k0 += 32) {
      const int kk = k0 + g8;
      bf16x8 a[2];
#pragma unroll
      for (int mf = 0; mf < 2; ++mf)
        a[mf] = *(const bf16x8*)(qh + (m_base + mf * 16 + r0) * 128 + kk);
#pragma unroll
      for (int nf = 0; nf < 4; ++nf) {
        const int d2 = wid * 64 + nf * 16 + r0;
        bf16x8 b = *(const bf16x8*)(kvsTh + d2 * 128 + kk);
#pragma unroll
        for (int mf = 0; mf < 2; ++mf) acc[mf][nf] = mfma_bf16(a[mf], b, acc[mf][nf]);
      }
    }
#pragma unroll
    for (int mf = 0; mf < 2; ++mf)
#pragma unroll
      for (int nf = 0; nf < 4; ++nf)
#pragma unroll
        for (int r = 0; r < 4; ++r) {
          const int s = m_base + mf * 16 + rr + r;
          const int d2 = wid * 64 + nf * 16 + r0;
          const float y = acc[mf][nf][r];
          const float u = 0.7978845608028654f * (y + 0.044715f * y * y * y);
          out[(size_t)s * 4096 + h * 128 + d2] = 0.5f * y * (1.f + tanhf(u));
        }
  } else {
    const int b2 = bid - 128;
    const int h = b2 >> 2, w = b2 & 3;
    const int m_base = w * 32;
    const __bf16* kTh = kdT + (size_t)h * 16384;
    const __bf16* vTh = vT + (size_t)h * 16384;

    f32x4 acc[2][4];
#pragma unroll
    for (int mf = 0; mf < 2; ++mf)
#pragma unroll
      for (int nf = 0; nf < 4; ++nf) acc[mf][nf] = (f32x4){0.f, 0.f, 0.f, 0.f};
#pragma unroll
    for (int k0 = 0; k0 < 128; k0 += 32) {
      const int kk = k0 + g8;
      bf16x8 a[2];
#pragma unroll
      for (int mf = 0; mf < 2; ++mf)
        a[mf] = *(const bf16x8*)(kTh + (m_base + mf * 16 + r0) * 128 + kk);
#pragma unroll
      for (int nf = 0; nf < 4; ++nf) {
        const int j = wid * 64 + nf * 16 + r0;
        bf16x8 b = *(const bf16x8*)(vTh + j * 128 + kk);
#pragma unroll
        for (int mf = 0; mf < 2; ++mf) acc[mf][nf] = mfma_bf16(a[mf], b, acc[mf][nf]);
      }
    }
#pragma unroll
    for (int mf = 0; mf < 2; ++mf)
#pragma unroll
      for (int nf = 0; nf < 4; ++nf)
#pragma unroll
        for (int r = 0; r < 4; ++r) {
          const int i = m_base + mf * 16 + rr + r;
          const int j = wid * 64 + nf * 16 + r0;
          const float dSi = exp2f(128.f * log2f(alpha[h * 128 + i]));
          const float val = acc[mf][nf][r] + kvs[(size_t)h * 16384 + i * 128 + j] * dSi;
          out[524288 + (size_t)h * 16384 + i * 128 + j] = val;
        }
  }
}

extern "C" void kernel_launch(void* const* d_in, const int* in_sizes, int n_in,
                              void* d_out, int out_size, void* d_ws, size_t ws_size,
                              hipStream_t stream) {
  const float* x = (const float*)d_in[0];      // (128, 4096)
  const float* W = (const float*)d_in[1];      // (12288, 4096)
  const float* alpha = (const float*)d_in[2];  // (32, 128)
  const float* kvs = (const float*)d_in[3];    // (32, 128, 128)
  float* out = (float*)d_out;

  char* ws = (char*)d_ws;
  __bf16* xb = (__bf16*)ws;                      // 1 MB
  __bf16* qd = (__bf16*)(ws + (1u << 20));       // 1 MB each
  __bf16* kd = (__bf16*)(ws + 2u * (1u << 20));
  __bf16* kdT = (__bf16*)(ws + 3u * (1u << 20));
  __bf16* vT = (__bf16*)(ws + 4u * (1u << 20));
  __bf16* kvsT = (__bf16*)(ws + 5u * (1u << 20));
  float* P = (float*)(ws + 6u * (1u << 20));     // KS * 6,291,456 B

  const size_t pbytes = ws_size > 6u * (1u << 20) ? ws_size - 6u * (1u << 20) : 0;
  int KS = 1;
  while (KS < 4 && (size_t)(KS * 2) * 6291456ull <= pbytes) KS *= 2;
  const int kc_len = 4096 / KS;

  prep_kernel<<<384, 256, 0, stream>>>(x, xb, kvs, alpha, kvsT);
  gemm_split_kernel<<<192 * KS, 256, 0, stream>>>(xb, W, P, kc_len);
  reduce_kernel<<<384, 256, 0, stream>>>(P, alpha, qd, kd, kdT, vT, KS);
  heads_kernel<<<256, 128, 0, stream>>>(qd, kd, kdT, vT, kvsT, kvs, alpha, out);
}

// Round 6
// 76.698 us; speedup vs baseline: 1.3595x; 1.2854x over previous
//
#include <hip/hip_runtime.h>
#include <hip/hip_bf16.h>

// EDMultiheadRetention: S=128, D=4096, H=32, hd=128
// Pipeline: prep (cast x + kvsT) -> gemm_split (KS=4 partials; A via global_load_lds
//           dbuf; W regs 2-deep; counted-vmcnt raw-barrier pipeline) -> reduce -> heads

typedef __bf16 bf16x8 __attribute__((ext_vector_type(8)));
typedef float f32x4 __attribute__((ext_vector_type(4)));

typedef __attribute__((address_space(1))) const unsigned g_u32;
typedef __attribute__((address_space(3))) unsigned l_u32;

static __device__ __forceinline__ f32x4 mfma_bf16(bf16x8 a, bf16x8 b, f32x4 c) {
  return __builtin_amdgcn_mfma_f32_16x16x32_bf16(a, b, c, 0, 0, 0);
}

static __device__ __forceinline__ bf16x8 cvt8(float4 lo, float4 hi) {
  return (bf16x8){(__bf16)lo.x, (__bf16)lo.y, (__bf16)lo.z, (__bf16)lo.w,
                  (__bf16)hi.x, (__bf16)hi.y, (__bf16)hi.z, (__bf16)hi.w};
}

#define WAIT_VM0() asm volatile("s_waitcnt vmcnt(0)" ::: "memory")
#define WAIT_VM4() asm volatile("s_waitcnt vmcnt(4)" ::: "memory")
#define WAIT_LGKM0() asm volatile("s_waitcnt lgkmcnt(0)" ::: "memory")
#define SCHED_FENCE() __builtin_amdgcn_sched_barrier(0)

// ---------------- kernel 1: cast x -> bf16 (blocks 0..255), kvsT prep (256..383)
__global__ __launch_bounds__(256) void prep_kernel(const float* __restrict__ x,
                                                   __bf16* __restrict__ xb,
                                                   const float* __restrict__ kvs,
                                                   const float* __restrict__ alpha,
                                                   __bf16* __restrict__ kvsT) {
  __shared__ float lds[32][129];
  const int tid = threadIdx.x;
  if (blockIdx.x < 256) {
    const int i = (blockIdx.x * 256 + tid) * 8;
    float4 a = *(const float4*)(x + i);
    float4 b = *(const float4*)(x + i + 4);
    *(bf16x8*)(xb + i) = cvt8(a, b);
    return;
  }
  const int bid = blockIdx.x - 256;
  const int h = bid >> 2, dq = bid & 3;
  const int j = tid & 127, dg = tid >> 7;
  const int d0 = dq * 32;
#pragma unroll
  for (int i = 0; i < 16; ++i) {
    const int dloc = dg * 16 + i;
    const int d = d0 + dloc;
    const float dS = exp2f(128.f * log2f(alpha[h * 128 + d]));
    lds[dloc][j] = kvs[(size_t)h * 16384 + d * 128 + j] * dS;
  }
  __syncthreads();
  const int jj = tid >> 1, dh = tid & 1;
  bf16x8 a0, a1;
#pragma unroll
  for (int i = 0; i < 8; ++i) a0[i] = (__bf16)lds[dh * 16 + i][jj];
#pragma unroll
  for (int i = 0; i < 8; ++i) a1[i] = (__bf16)lds[dh * 16 + 8 + i][jj];
  *(bf16x8*)(kvsT + (size_t)h * 16384 + jj * 128 + d0 + dh * 16) = a0;
  *(bf16x8*)(kvsT + (size_t)h * 16384 + jj * 128 + d0 + dh * 16 + 8) = a1;
}

// ---------------- kernel 2: split-K GEMM: P[ks][s][n] = x @ W^T (partial) ---
// 256 thr (4 waves 2x2), tile M=128 x N=64, BK=64.
// A: global_load_lds into XOR-swizzled LDS, double-buffered, issued 1 iter ahead.
// W: f32 reg loads 2 tiles ahead; cvt->bf16 -> swizzled ds_write 1 tile ahead.
// Raw s_barrier + counted vmcnt: W(t+2) loads stay in flight across the barrier.
__global__ __launch_bounds__(256, 3) void gemm_split_kernel(const __bf16* __restrict__ xb,
                                                            const float* __restrict__ W,
                                                            float* __restrict__ P,
                                                            int kc_len) {
  __shared__ __bf16 Ald[2][128 * 64];
  __shared__ __bf16 Bld[2][64 * 64];

  const int tid = threadIdx.x;
  const int wid = tid >> 6, lane = tid & 63;
  const int r0 = lane & 15, l4 = lane >> 4, rr = l4 << 2;
  const int nt = blockIdx.x % 192, ks = blockIdx.x / 192;
  const int n0 = nt * 64;
  const int kb0 = ks * kc_len;
  const int wm = wid & 1, wn = wid >> 1;

  // A staging: 4 DMA units/thread; unit u -> (row=u>>3, phys chunk p=u&7),
  // source logical chunk g = p ^ (row&7); LDS dest linear (u*16 bytes).
  int a_row[4], a_koff[4];
#pragma unroll
  for (int i = 0; i < 4; ++i) {
    const int u = i * 256 + tid;
    a_row[i] = u >> 3;
    a_koff[i] = ((u & 7) ^ (a_row[i] & 7)) << 3;
  }
  // B staging: 2 units/thread, reg-staged f32->bf16, swizzled ds_write
  int b_elem[2];
  const float* wp[2];
#pragma unroll
  for (int i = 0; i < 2; ++i) {
    const int u = i * 256 + tid;
    const int row = u >> 3;
    const int p = u & 7;
    const int koff = (p ^ (row & 7)) << 3;
    b_elem[i] = row * 64 + p * 8;
    wp[i] = W + (size_t)(n0 + row) * 4096 + kb0 + koff;
  }

  // fragment read offsets: logical chunk c = kh*4+l4, phys = c^(row&7)
  int a_off[4][2], b_off[2][2];
#pragma unroll
  for (int mf = 0; mf < 4; ++mf)
#pragma unroll
    for (int kh = 0; kh < 2; ++kh) {
      const int row = wm * 64 + mf * 16 + r0;
      const int p = (kh * 4 + l4) ^ (row & 7);
      a_off[mf][kh] = row * 64 + p * 8;
    }
#pragma unroll
  for (int nf = 0; nf < 2; ++nf)
#pragma unroll
    for (int kh = 0; kh < 2; ++kh) {
      const int row = wn * 32 + nf * 16 + r0;
      const int p = (kh * 4 + l4) ^ (row & 7);
      b_off[nf][kh] = row * 64 + p * 8;
    }

  f32x4 acc[4][2];
#pragma unroll
  for (int mf = 0; mf < 4; ++mf)
#pragma unroll
    for (int nf = 0; nf < 2; ++nf) acc[mf][nf] = (f32x4){0.f, 0.f, 0.f, 0.f};

  const int iters = kc_len >> 6;  // 16 at KS=4 (always even)

  float4 w0lo[2], w0hi[2], w1lo[2], w1hi[2];

  // ---- prologue: A(0)->Ald[0]; W(0)->w0; W(1)->w1; B(0) written from w0
#pragma unroll
  for (int i = 0; i < 4; ++i) {
    const __bf16* src = xb + a_row[i] * 4096 + kb0 + a_koff[i];
    __builtin_amdgcn_global_load_lds((g_u32*)(const void*)src,
                                     (l_u32*)(void*)((char*)&Ald[0][0] + i * 4096 + wid * 1024),
                                     16, 0, 0);
  }
#pragma unroll
  for (int i = 0; i < 2; ++i) {
    w0lo[i] = *(const float4*)(wp[i]);
    w0hi[i] = *(const float4*)(wp[i] + 4);
  }
  if (iters > 1) {
#pragma unroll
    for (int i = 0; i < 2; ++i) {
      w1lo[i] = *(const float4*)(wp[i] + 64);
      w1hi[i] = *(const float4*)(wp[i] + 64 + 4);
    }
  }
#pragma unroll
  for (int i = 0; i < 2; ++i) *(bf16x8*)(&Bld[0][b_elem[i]]) = cvt8(w0lo[i], w0hi[i]);
  if (iters > 1) { WAIT_VM4(); } else { WAIT_VM0(); }  // A(0)+W(0) done; W(1) in flight
  WAIT_LGKM0();
  SCHED_FENCE();
  __builtin_amdgcn_s_barrier();

// per-iteration body. T = tile idx; CUR = buffer; WR* = regs holding W(T+1);
// LD* = regs to receive W(T+2).
#define GEMM_ITER(T, CUR, WRLO, WRHI, LDLO, LDHI)                                        \
  do {                                                                                   \
    const bool hn1 = (T) + 1 < iters, hn2 = (T) + 2 < iters;                             \
    if (hn1) {                                                                           \
      const int kb = kb0 + ((T) + 1) * 64;                                               \
      _Pragma("unroll") for (int i = 0; i < 4; ++i) {                                    \
        const __bf16* src = xb + a_row[i] * 4096 + kb + a_koff[i];                       \
        __builtin_amdgcn_global_load_lds(                                                \
            (g_u32*)(const void*)src,                                                    \
            (l_u32*)(void*)((char*)&Ald[1 - (CUR)][0] + i * 4096 + wid * 1024), 16, 0, 0); \
      }                                                                                  \
    }                                                                                    \
    if (hn2) {                                                                           \
      const int kb = ((T) + 2) * 64;                                                     \
      _Pragma("unroll") for (int i = 0; i < 2; ++i) {                                    \
        LDLO[i] = *(const float4*)(wp[i] + kb);                                          \
        LDHI[i] = *(const float4*)(wp[i] + kb + 4);                                      \
      }                                                                                  \
    }                                                                                    \
    bf16x8 af[4][2], bfr[2][2];                                                          \
    _Pragma("unroll") for (int kh = 0; kh < 2; ++kh) {                                   \
      _Pragma("unroll") for (int mf = 0; mf < 4; ++mf)                                   \
          af[mf][kh] = *(const bf16x8*)(&Ald[CUR][a_off[mf][kh]]);                       \
      _Pragma("unroll") for (int nf = 0; nf < 2; ++nf)                                   \
          bfr[nf][kh] = *(const bf16x8*)(&Bld[CUR][b_off[nf][kh]]);                      \
    }                                                                                    \
    _Pragma("unroll") for (int kh = 0; kh < 2; ++kh)                                     \
        _Pragma("unroll") for (int mf = 0; mf < 4; ++mf)                                 \
            _Pragma("unroll") for (int nf = 0; nf < 2; ++nf)                             \
                acc[mf][nf] = mfma_bf16(af[mf][kh], bfr[nf][kh], acc[mf][nf]);           \
    SCHED_FENCE(); /* keep cvt/ds_write (and its vmcnt wait) below the MFMAs */          \
    if (hn1) {                                                                           \
      _Pragma("unroll") for (int i = 0; i < 2; ++i)                                      \
          *(bf16x8*)(&Bld[1 - (CUR)][b_elem[i]]) = cvt8(WRLO[i], WRHI[i]);               \
      if (hn2) { WAIT_VM4(); } else { WAIT_VM0(); } /* A(T+1) landed; W(T+2) in flight */ \
      WAIT_LGKM0();                                                                      \
      SCHED_FENCE();                                                                     \
      __builtin_amdgcn_s_barrier();                                                      \
    }                                                                                    \
  } while (0)

  for (int t = 0; t < iters; t += 2) {
    GEMM_ITER(t, 0, w1lo, w1hi, w0lo, w0hi);
    if (t + 1 < iters) GEMM_ITER(t + 1, 1, w0lo, w0hi, w1lo, w1hi);
  }
#undef GEMM_ITER

  // epilogue: write partials P[ks][s][n]
#pragma unroll
  for (int mf = 0; mf < 4; ++mf)
#pragma unroll
    for (int nf = 0; nf < 2; ++nf)
#pragma unroll
      for (int r = 0; r < 4; ++r) {
        const int s = wm * 64 + mf * 16 + rr + r;
        const int n = n0 + wn * 32 + nf * 16 + r0;
        P[(size_t)ks * 1572864 + (size_t)s * 12288 + n] = acc[mf][nf][r];
      }
}

// ---------------- kernel 3: reduce partials, apply decay, emit bf16 layouts
// qd/kd [h][s][d], kdT/vT [h][d][s]
__global__ __launch_bounds__(256) void reduce_kernel(const float* __restrict__ P,
                                                     const float* __restrict__ alpha,
                                                     __bf16* __restrict__ qd,
                                                     __bf16* __restrict__ kd,
                                                     __bf16* __restrict__ kdT,
                                                     __bf16* __restrict__ vT, int KS) {
  __shared__ float lds[32][129];
  const int bid = blockIdx.x;
  const int which = bid >> 7;  // 0=q 1=k 2=v
  const int rem = bid & 127;
  const int h = rem >> 2, sq = rem & 3;
  const int tid = threadIdx.x;
  const int d = tid & 127, sg = tid >> 7;
  const int n = which * 4096 + h * 128 + d;
  const int s0 = sq * 32;
  const float la = log2f(alpha[h * 128 + d]);

#pragma unroll 4
  for (int si = 0; si < 16; ++si) {
    const int s = s0 + sg * 16 + si;
    float val = 0.f;
#pragma unroll
    for (int ksi = 0; ksi < 4; ++ksi)
      if (ksi < KS) val += P[(size_t)ksi * 1572864 + (size_t)s * 12288 + n];
    if (which == 0)
      val *= exp2f((float)(s - 127) * la - 6.0f);
    else if (which == 1)
      val *= exp2f((float)(127 - s) * la - 6.0f);
    lds[sg * 16 + si][d] = val;
    if (which == 0)
      qd[(size_t)h * 16384 + s * 128 + d] = (__bf16)val;
    else if (which == 1)
      kd[(size_t)h * 16384 + s * 128 + d] = (__bf16)val;
  }
  if (which == 0) return;
  __syncthreads();
  __bf16* outT = (which == 1 ? kdT : vT) + (size_t)h * 16384;
  const int dd = tid >> 1, sh = tid & 1;
  bf16x8 v0, v1;
#pragma unroll
  for (int i = 0; i < 8; ++i) v0[i] = (__bf16)lds[sh * 16 + i][dd];
#pragma unroll
  for (int i = 0; i < 8; ++i) v1[i] = (__bf16)lds[sh * 16 + 8 + i][dd];
  *(bf16x8*)(outT + dd * 128 + s0 + sh * 16) = v0;
  *(bf16x8*)(outT + dd * 128 + s0 + sh * 16 + 8) = v1;
}

// ---------------- kernel 4: per-head retention (all contiguous bf16 loads) --
// bid<128: out rows; bid>=128: new_kvs rows. 128 threads (2 waves).
__global__ __launch_bounds__(128) void heads_kernel(const __bf16* __restrict__ qd,
                                                    const __bf16* __restrict__ kd,
                                                    const __bf16* __restrict__ kdT,
                                                    const __bf16* __restrict__ vT,
                                                    const __bf16* __restrict__ kvsT,
                                                    const float* __restrict__ kvs,
                                                    const float* __restrict__ alpha,
                                                    float* __restrict__ out) {
  const int bid = blockIdx.x;
  const int tid = threadIdx.x;
  const int wid = tid >> 6, lane = tid & 63;
  const int r0 = lane & 15, l4 = lane >> 4;
  const int g8 = l4 << 3, rr = l4 << 2;

  if (bid < 128) {
    const int h = bid >> 2, w = bid & 3;
    const int m_base = w * 32;
    __shared__ __bf16 attn_s[32][136];
    const __bf16* qh = qd + (size_t)h * 16384;
    const __bf16* kh = kd + (size_t)h * 16384;

    f32x4 acc[2][4];
#pragma unroll
    for (int mf = 0; mf < 2; ++mf)
#pragma unroll
      for (int nf = 0; nf < 4; ++nf) acc[mf][nf] = (f32x4){0.f, 0.f, 0.f, 0.f};

    // phase 1: attn cols wid*64..+64
#pragma unroll
    for (int k0 = 0; k0 < 128; k0 += 32) {
      const int kk = k0 + g8;
      bf16x8 a[2];
#pragma unroll
      for (int mf = 0; mf < 2; ++mf)
        a[mf] = *(const bf16x8*)(qh + (m_base + mf * 16 + r0) * 128 + kk);
#pragma unroll
      for (int nf = 0; nf < 4; ++nf) {
        const int jn = wid * 64 + nf * 16 + r0;
        bf16x8 b = *(const bf16x8*)(kh + jn * 128 + kk);
#pragma unroll
        for (int mf = 0; mf < 2; ++mf) acc[mf][nf] = mfma_bf16(a[mf], b, acc[mf][nf]);
      }
    }
#pragma unroll
    for (int mf = 0; mf < 2; ++mf)
#pragma unroll
      for (int nf = 0; nf < 4; ++nf)
#pragma unroll
        for (int r = 0; r < 4; ++r) {
          const int i = m_base + mf * 16 + rr + r;
          const int j = wid * 64 + nf * 16 + r0;
          attn_s[mf * 16 + rr + r][j] = (__bf16)((j <= i) ? acc[mf][nf][r] : 0.f);
        }
    __syncthreads();

    // phase 2: out = gelu(attn @ v + q @ kvsT), d2 in wid*64..+64
#pragma unroll
    for (int mf = 0; mf < 2; ++mf)
#pragma unroll
      for (int nf = 0; nf < 4; ++nf) acc[mf][nf] = (f32x4){0.f, 0.f, 0.f, 0.f};
    const __bf16* vTh = vT + (size_t)h * 16384;
    const __bf16* kvsTh = kvsT + (size_t)h * 16384;
#pragma unroll
    for (int k0 = 0; k0 < 128; k0 += 32) {
      const int kk = k0 + g8;
      bf16x8 a[2];
#pragma unroll
      for (int mf = 0; mf < 2; ++mf)
        a[mf] = *(const bf16x8*)(&attn_s[mf * 16 + r0][kk]);
#pragma unroll
      for (int nf = 0; nf < 4; ++nf) {
        const int d2 = wid * 64 + nf * 16 + r0;
        bf16x8 b = *(const bf16x8*)(vTh + d2 * 128 + kk);
#pragma unroll
        for (int mf = 0; mf < 2; ++mf) acc[mf][nf] = mfma_bf16(a[mf], b, acc[mf][nf]);
      }
    }
#pragma unroll
    for (int k0 = 0; k0 < 128; k0 += 32) {
      const int kk = k0 + g8;
      bf16x8 a[2];
#pragma unroll
      for (int mf = 0; mf < 2; ++mf)
        a[mf] = *(const bf16x8*)(qh + (m_base + mf * 16 + r0) * 128 + kk);
#pragma unroll
      for (int nf = 0; nf < 4; ++nf) {
        const int d2 = wid * 64 + nf * 16 + r0;
        bf16x8 b = *(const bf16x8*)(kvsTh + d2 * 128 + kk);
#pragma unroll
        for (int mf = 0; mf < 2; ++mf) acc[mf][nf] = mfma_bf16(a[mf], b, acc[mf][nf]);
      }
    }
#pragma unroll
    for (int mf = 0; mf < 2; ++mf)
#pragma unroll
      for (int nf = 0; nf < 4; ++nf)
#pragma unroll
        for (int r = 0; r < 4; ++r) {
          const int s = m_base + mf * 16 + rr + r;
          const int d2 = wid * 64 + nf * 16 + r0;
          const float y = acc[mf][nf][r];
          const float u = 0.7978845608028654f * (y + 0.044715f * y * y * y);
          out[(size_t)s * 4096 + h * 128 + d2] = 0.5f * y * (1.f + tanhf(u));
        }
  } else {
    const int b2 = bid - 128;
    const int h = b2 >> 2, w = b2 & 3;
    const int m_base = w * 32;
    const __bf16* kTh = kdT + (size_t)h * 16384;
    const __bf16* vTh = vT + (size_t)h * 16384;

    f32x4 acc[2][4];
#pragma unroll
    for (int mf = 0; mf < 2; ++mf)
#pragma unroll
      for (int nf = 0; nf < 4; ++nf) acc[mf][nf] = (f32x4){0.f, 0.f, 0.f, 0.f};
#pragma unroll
    for (int k0 = 0; k0 < 128; k0 += 32) {
      const int kk = k0 + g8;
      bf16x8 a[2];
#pragma unroll
      for (int mf = 0; mf < 2; ++mf)
        a[mf] = *(const bf16x8*)(kTh + (m_base + mf * 16 + r0) * 128 + kk);
#pragma unroll
      for (int nf = 0; nf < 4; ++nf) {
        const int j = wid * 64 + nf * 16 + r0;
        bf16x8 b = *(const bf16x8*)(vTh + j * 128 + kk);
#pragma unroll
        for (int mf = 0; mf < 2; ++mf) acc[mf][nf] = mfma_bf16(a[mf], b, acc[mf][nf]);
      }
    }
#pragma unroll
    for (int mf = 0; mf < 2; ++mf)
#pragma unroll
      for (int nf = 0; nf < 4; ++nf)
#pragma unroll
        for (int r = 0; r < 4; ++r) {
          const int i = m_base + mf * 16 + rr + r;
          const int j = wid * 64 + nf * 16 + r0;
          const float dSi = exp2f(128.f * log2f(alpha[h * 128 + i]));
          const float val = acc[mf][nf][r] + kvs[(size_t)h * 16384 + i * 128 + j] * dSi;
          out[524288 + (size_t)h * 16384 + i * 128 + j] = val;
        }
  }
}

extern "C" void kernel_launch(void* const* d_in, const int* in_sizes, int n_in,
                              void* d_out, int out_size, void* d_ws, size_t ws_size,
                              hipStream_t stream) {
  const float* x = (const float*)d_in[0];      // (128, 4096)
  const float* W = (const float*)d_in[1];      // (12288, 4096)
  const float* alpha = (const float*)d_in[2];  // (32, 128)
  const float* kvs = (const float*)d_in[3];    // (32, 128, 128)
  float* out = (float*)d_out;

  char* ws = (char*)d_ws;
  __bf16* xb = (__bf16*)ws;                      // 1 MB
  __bf16* qd = (__bf16*)(ws + (1u << 20));       // 1 MB each
  __bf16* kd = (__bf16*)(ws + 2u * (1u << 20));
  __bf16* kdT = (__bf16*)(ws + 3u * (1u << 20));
  __bf16* vT = (__bf16*)(ws + 4u * (1u << 20));
  __bf16* kvsT = (__bf16*)(ws + 5u * (1u << 20));
  float* P = (float*)(ws + 6u * (1u << 20));     // KS * 6,291,456 B

  const size_t pbytes = ws_size > 6u * (1u << 20) ? ws_size - 6u * (1u << 20) : 0;
  int KS = 1;
  while (KS < 4 && (size_t)(KS * 2) * 6291456ull <= pbytes) KS *= 2;
  const int kc_len = 4096 / KS;

  prep_kernel<<<384, 256, 0, stream>>>(x, xb, kvs, alpha, kvsT);
  gemm_split_kernel<<<192 * KS, 256, 0, stream>>>(xb, W, P, kc_len);
  reduce_kernel<<<384, 256, 0, stream>>>(P, alpha, qd, kd, kdT, vT, KS);
  heads_kernel<<<256, 128, 0, stream>>>(qd, kd, kdT, vT, kvsT, kvs, alpha, out);
}

// Round 7
// 76.149 us; speedup vs baseline: 1.3692x; 1.0072x over previous
//
#include <hip/hip_runtime.h>
#include <hip/hip_bf16.h>

// EDMultiheadRetention: S=128, D=4096, H=32, hd=128
// Pipeline: prep (cast x + kvsT) -> gemm_split (KS=4; BK=32; 4 blocks/CU;
//           A via global_load_lds dbuf; W regs 2-deep; counted-vmcnt) -> reduce -> heads

typedef __bf16 bf16x8 __attribute__((ext_vector_type(8)));
typedef float f32x4 __attribute__((ext_vector_type(4)));

typedef __attribute__((address_space(1))) const unsigned g_u32;
typedef __attribute__((address_space(3))) unsigned l_u32;

static __device__ __forceinline__ f32x4 mfma_bf16(bf16x8 a, bf16x8 b, f32x4 c) {
  return __builtin_amdgcn_mfma_f32_16x16x32_bf16(a, b, c, 0, 0, 0);
}

static __device__ __forceinline__ bf16x8 cvt8(float4 lo, float4 hi) {
  return (bf16x8){(__bf16)lo.x, (__bf16)lo.y, (__bf16)lo.z, (__bf16)lo.w,
                  (__bf16)hi.x, (__bf16)hi.y, (__bf16)hi.z, (__bf16)hi.w};
}

#define WAIT_VM0() asm volatile("s_waitcnt vmcnt(0)" ::: "memory")
#define WAIT_VM2() asm volatile("s_waitcnt vmcnt(2)" ::: "memory")
#define WAIT_LGKM0() asm volatile("s_waitcnt lgkmcnt(0)" ::: "memory")
#define SCHED_FENCE() __builtin_amdgcn_sched_barrier(0)

// ---------------- kernel 1: cast x -> bf16 (blocks 0..255), kvsT prep (256..383)
__global__ __launch_bounds__(256) void prep_kernel(const float* __restrict__ x,
                                                   __bf16* __restrict__ xb,
                                                   const float* __restrict__ kvs,
                                                   const float* __restrict__ alpha,
                                                   __bf16* __restrict__ kvsT) {
  __shared__ float lds[32][129];
  const int tid = threadIdx.x;
  if (blockIdx.x < 256) {
    const int i = (blockIdx.x * 256 + tid) * 8;
    float4 a = *(const float4*)(x + i);
    float4 b = *(const float4*)(x + i + 4);
    *(bf16x8*)(xb + i) = cvt8(a, b);
    return;
  }
  const int bid = blockIdx.x - 256;
  const int h = bid >> 2, dq = bid & 3;
  const int j = tid & 127, dg = tid >> 7;
  const int d0 = dq * 32;
#pragma unroll
  for (int i = 0; i < 16; ++i) {
    const int dloc = dg * 16 + i;
    const int d = d0 + dloc;
    const float dS = exp2f(128.f * log2f(alpha[h * 128 + d]));
    lds[dloc][j] = kvs[(size_t)h * 16384 + d * 128 + j] * dS;
  }
  __syncthreads();
  const int jj = tid >> 1, dh = tid & 1;
  bf16x8 a0, a1;
#pragma unroll
  for (int i = 0; i < 8; ++i) a0[i] = (__bf16)lds[dh * 16 + i][jj];
#pragma unroll
  for (int i = 0; i < 8; ++i) a1[i] = (__bf16)lds[dh * 16 + 8 + i][jj];
  *(bf16x8*)(kvsT + (size_t)h * 16384 + jj * 128 + d0 + dh * 16) = a0;
  *(bf16x8*)(kvsT + (size_t)h * 16384 + jj * 128 + d0 + dh * 16 + 8) = a1;
}

// ---------------- kernel 2: split-K GEMM: P[ks][s][n] = x @ W^T (partial) ---
// 256 thr (4 waves 2x2), tile M=128 x N=64, BK=32, 24 KB LDS -> 4 blocks/CU.
// A: global_load_lds into XOR-swizzled LDS (p = c ^ ((row>>1)&3)), dbuf, 1 iter ahead.
// W: f32 reg loads 2 tiles ahead; cvt->bf16 -> swizzled ds_write 1 tile ahead.
// Raw s_barrier + counted vmcnt: W(t+2) loads stay in flight across the barrier.
__global__ __launch_bounds__(256, 4) void gemm_split_kernel(const __bf16* __restrict__ xb,
                                                            const float* __restrict__ W,
                                                            float* __restrict__ P,
                                                            int kc_len) {
  __shared__ __bf16 Ald[2][128 * 32];
  __shared__ __bf16 Bld[2][64 * 32];

  const int tid = threadIdx.x;
  const int wid = tid >> 6, lane = tid & 63;
  const int r0 = lane & 15, l4 = lane >> 4, rr = l4 << 2;
  const int nt = blockIdx.x % 192, ks = blockIdx.x / 192;
  const int n0 = nt * 64;
  const int kb0 = ks * kc_len;
  const int wm = wid & 1, wn = wid >> 1;

  // A staging: 2 DMA units/thread; unit u -> (row=u>>2, phys chunk p=u&3),
  // source logical chunk g = p ^ ((row>>1)&3); LDS dest linear (u*16 bytes).
  int a_row[2], a_koff[2];
#pragma unroll
  for (int i = 0; i < 2; ++i) {
    const int u = i * 256 + tid;
    a_row[i] = u >> 2;
    a_koff[i] = ((u & 3) ^ ((a_row[i] >> 1) & 3)) << 3;
  }
  // B staging: 1 unit/thread, reg-staged f32->bf16, swizzled ds_write
  const int b_row = tid >> 2;
  const int b_p = tid & 3;
  const int b_g = b_p ^ ((b_row >> 1) & 3);
  const int b_elem = b_row * 32 + b_p * 8;
  const float* wp = W + (size_t)(n0 + b_row) * 4096 + kb0 + (b_g << 3);

  // fragment read offsets: logical chunk c = l4, phys = c ^ ((row>>1)&3)
  int a_off[4], b_off[2];
#pragma unroll
  for (int mf = 0; mf < 4; ++mf) {
    const int row = wm * 64 + mf * 16 + r0;
    const int p = l4 ^ ((row >> 1) & 3);
    a_off[mf] = row * 32 + p * 8;
  }
#pragma unroll
  for (int nf = 0; nf < 2; ++nf) {
    const int row = wn * 32 + nf * 16 + r0;
    const int p = l4 ^ ((row >> 1) & 3);
    b_off[nf] = row * 32 + p * 8;
  }

  f32x4 acc[4][2];
#pragma unroll
  for (int mf = 0; mf < 4; ++mf)
#pragma unroll
    for (int nf = 0; nf < 2; ++nf) acc[mf][nf] = (f32x4){0.f, 0.f, 0.f, 0.f};

  const int iters = kc_len >> 5;  // 32 at KS=4 (always even)

  float4 w0lo, w0hi, w1lo, w1hi;

  // ---- prologue: A(0)->Ald[0]; W(0)->w0; W(1)->w1; B(0) written from w0
#pragma unroll
  for (int i = 0; i < 2; ++i) {
    const __bf16* src = xb + a_row[i] * 4096 + kb0 + a_koff[i];
    __builtin_amdgcn_global_load_lds((g_u32*)(const void*)src,
                                     (l_u32*)(void*)((char*)&Ald[0][0] + i * 4096 + tid * 16),
                                     16, 0, 0);
  }
  w0lo = *(const float4*)(wp);
  w0hi = *(const float4*)(wp + 4);
  if (iters > 1) {
    w1lo = *(const float4*)(wp + 32);
    w1hi = *(const float4*)(wp + 32 + 4);
  }
  *(bf16x8*)(&Bld[0][b_elem]) = cvt8(w0lo, w0hi);
  if (iters > 1) { WAIT_VM2(); } else { WAIT_VM0(); }  // A(0)+W(0) done; W(1) in flight
  WAIT_LGKM0();
  SCHED_FENCE();
  __builtin_amdgcn_s_barrier();

// per-iteration body. T = tile idx; CUR = buffer; WR* = regs holding W(T+1);
// LD* = regs to receive W(T+2).
#define GEMM_ITER(T, CUR, WRLO, WRHI, LDLO, LDHI)                                        \
  do {                                                                                   \
    const bool hn1 = (T) + 1 < iters, hn2 = (T) + 2 < iters;                             \
    if (hn1) {                                                                           \
      const int kb = kb0 + ((T) + 1) * 32;                                               \
      _Pragma("unroll") for (int i = 0; i < 2; ++i) {                                    \
        const __bf16* src = xb + a_row[i] * 4096 + kb + a_koff[i];                       \
        __builtin_amdgcn_global_load_lds(                                                \
            (g_u32*)(const void*)src,                                                    \
            (l_u32*)(void*)((char*)&Ald[1 - (CUR)][0] + i * 4096 + tid * 16), 16, 0, 0); \
      }                                                                                  \
    }                                                                                    \
    if (hn2) {                                                                           \
      const int kb = ((T) + 2) * 32;                                                     \
      LDLO = *(const float4*)(wp + kb);                                                  \
      LDHI = *(const float4*)(wp + kb + 4);                                              \
    }                                                                                    \
    SCHED_FENCE(); /* all staging issued before compute */                               \
    bf16x8 af[4], bfr[2];                                                                \
    _Pragma("unroll") for (int mf = 0; mf < 4; ++mf)                                     \
        af[mf] = *(const bf16x8*)(&Ald[CUR][a_off[mf]]);                                 \
    _Pragma("unroll") for (int nf = 0; nf < 2; ++nf)                                     \
        bfr[nf] = *(const bf16x8*)(&Bld[CUR][b_off[nf]]);                                \
    _Pragma("unroll") for (int mf = 0; mf < 4; ++mf)                                     \
        _Pragma("unroll") for (int nf = 0; nf < 2; ++nf)                                 \
            acc[mf][nf] = mfma_bf16(af[mf], bfr[nf], acc[mf][nf]);                       \
    SCHED_FENCE(); /* keep cvt/ds_write (and its vmcnt wait) below the MFMAs */          \
    if (hn1) {                                                                           \
      *(bf16x8*)(&Bld[1 - (CUR)][b_elem]) = cvt8(WRLO, WRHI);                            \
      if (hn2) { WAIT_VM2(); } else { WAIT_VM0(); } /* A(T+1) landed; W(T+2) flying */   \
      WAIT_LGKM0();                                                                      \
      SCHED_FENCE();                                                                     \
      __builtin_amdgcn_s_barrier();                                                      \
    }                                                                                    \
  } while (0)

  for (int t = 0; t < iters; t += 2) {
    GEMM_ITER(t, 0, w1lo, w1hi, w0lo, w0hi);
    if (t + 1 < iters) GEMM_ITER(t + 1, 1, w0lo, w0hi, w1lo, w1hi);
  }
#undef GEMM_ITER

  // epilogue: write partials P[ks][s][n]
#pragma unroll
  for (int mf = 0; mf < 4; ++mf)
#pragma unroll
    for (int nf = 0; nf < 2; ++nf)
#pragma unroll
      for (int r = 0; r < 4; ++r) {
        const int s = wm * 64 + mf * 16 + rr + r;
        const int n = n0 + wn * 32 + nf * 16 + r0;
        P[(size_t)ks * 1572864 + (size_t)s * 12288 + n] = acc[mf][nf][r];
      }
}

// ---------------- kernel 3: reduce partials, apply decay, emit bf16 layouts
// qd/kd [h][s][d], kdT/vT [h][d][s]
__global__ __launch_bounds__(256) void reduce_kernel(const float* __restrict__ P,
                                                     const float* __restrict__ alpha,
                                                     __bf16* __restrict__ qd,
                                                     __bf16* __restrict__ kd,
                                                     __bf16* __restrict__ kdT,
                                                     __bf16* __restrict__ vT, int KS) {
  __shared__ float lds[32][129];
  const int bid = blockIdx.x;
  const int which = bid >> 7;  // 0=q 1=k 2=v
  const int rem = bid & 127;
  const int h = rem >> 2, sq = rem & 3;
  const int tid = threadIdx.x;
  const int d = tid & 127, sg = tid >> 7;
  const int n = which * 4096 + h * 128 + d;
  const int s0 = sq * 32;
  const float la = log2f(alpha[h * 128 + d]);

#pragma unroll 4
  for (int si = 0; si < 16; ++si) {
    const int s = s0 + sg * 16 + si;
    float val = 0.f;
#pragma unroll
    for (int ksi = 0; ksi < 4; ++ksi)
      if (ksi < KS) val += P[(size_t)ksi * 1572864 + (size_t)s * 12288 + n];
    if (which == 0)
      val *= exp2f((float)(s - 127) * la - 6.0f);
    else if (which == 1)
      val *= exp2f((float)(127 - s) * la - 6.0f);
    lds[sg * 16 + si][d] = val;
    if (which == 0)
      qd[(size_t)h * 16384 + s * 128 + d] = (__bf16)val;
    else if (which == 1)
      kd[(size_t)h * 16384 + s * 128 + d] = (__bf16)val;
  }
  if (which == 0) return;
  __syncthreads();
  __bf16* outT = (which == 1 ? kdT : vT) + (size_t)h * 16384;
  const int dd = tid >> 1, sh = tid & 1;
  bf16x8 v0, v1;
#pragma unroll
  for (int i = 0; i < 8; ++i) v0[i] = (__bf16)lds[sh * 16 + i][dd];
#pragma unroll
  for (int i = 0; i < 8; ++i) v1[i] = (__bf16)lds[sh * 16 + 8 + i][dd];
  *(bf16x8*)(outT + dd * 128 + s0 + sh * 16) = v0;
  *(bf16x8*)(outT + dd * 128 + s0 + sh * 16 + 8) = v1;
}

// ---------------- kernel 4: per-head retention (all contiguous bf16 loads) --
// bid<128: out rows; bid>=128: new_kvs rows. 128 threads (2 waves).
__global__ __launch_bounds__(128) void heads_kernel(const __bf16* __restrict__ qd,
                                                    const __bf16* __restrict__ kd,
                                                    const __bf16* __restrict__ kdT,
                                                    const __bf16* __restrict__ vT,
                                                    const __bf16* __restrict__ kvsT,
                                                    const float* __restrict__ kvs,
                                                    const float* __restrict__ alpha,
                                                    float* __restrict__ out) {
  const int bid = blockIdx.x;
  const int tid = threadIdx.x;
  const int wid = tid >> 6, lane = tid & 63;
  const int r0 = lane & 15, l4 = lane >> 4;
  const int g8 = l4 << 3, rr = l4 << 2;

  if (bid < 128) {
    const int h = bid >> 2, w = bid & 3;
    const int m_base = w * 32;
    __shared__ __bf16 attn_s[32][136];
    const __bf16* qh = qd + (size_t)h * 16384;
    const __bf16* kh = kd + (size_t)h * 16384;

    f32x4 acc[2][4];
#pragma unroll
    for (int mf = 0; mf < 2; ++mf)
#pragma unroll
      for (int nf = 0; nf < 4; ++nf) acc[mf][nf] = (f32x4){0.f, 0.f, 0.f, 0.f};

    // phase 1: attn cols wid*64..+64
#pragma unroll
    for (int k0 = 0; k0 < 128; k0 += 32) {
      const int kk = k0 + g8;
      bf16x8 a[2];
#pragma unroll
      for (int mf = 0; mf < 2; ++mf)
        a[mf] = *(const bf16x8*)(qh + (m_base + mf * 16 + r0) * 128 + kk);
#pragma unroll
      for (int nf = 0; nf < 4; ++nf) {
        const int jn = wid * 64 + nf * 16 + r0;
        bf16x8 b = *(const bf16x8*)(kh + jn * 128 + kk);
#pragma unroll
        for (int mf = 0; mf < 2; ++mf) acc[mf][nf] = mfma_bf16(a[mf], b, acc[mf][nf]);
      }
    }
#pragma unroll
    for (int mf = 0; mf < 2; ++mf)
#pragma unroll
      for (int nf = 0; nf < 4; ++nf)
#pragma unroll
        for (int r = 0; r < 4; ++r) {
          const int i = m_base + mf * 16 + rr + r;
          const int j = wid * 64 + nf * 16 + r0;
          attn_s[mf * 16 + rr + r][j] = (__bf16)((j <= i) ? acc[mf][nf][r] : 0.f);
        }
    __syncthreads();

    // phase 2: out = gelu(attn @ v + q @ kvsT), d2 in wid*64..+64
#pragma unroll
    for (int mf = 0; mf < 2; ++mf)
#pragma unroll
      for (int nf = 0; nf < 4; ++nf) acc[mf][nf] = (f32x4){0.f, 0.f, 0.f, 0.f};
    const __bf16* vTh = vT + (size_t)h * 16384;
    const __bf16* kvsTh = kvsT + (size_t)h * 16384;
#pragma unroll
    for (int k0 = 0; k0 < 128; k0 += 32) {
      const int kk = k0 + g8;
      bf16x8 a[2];
#pragma unroll
      for (int mf = 0; mf < 2; ++mf)
        a[mf] = *(const bf16x8*)(&attn_s[mf * 16 + r0][kk]);
#pragma unroll
      for (int nf = 0; nf < 4; ++nf) {
        const int d2 = wid * 64 + nf * 16 + r0;
        bf16x8 b = *(const bf16x8*)(vTh + d2 * 128 + kk);
#pragma unroll
        for (int mf = 0; mf < 2; ++mf) acc[mf][nf] = mfma_bf16(a[mf], b, acc[mf][nf]);
      }
    }
#pragma unroll
    for (int k0 = 0; k0 < 128; k0 += 32) {
      const int kk = k0 + g8;
      bf16x8 a[2];
#pragma unroll
      for (int mf = 0; mf < 2; ++mf)
        a[mf] = *(const bf16x8*)(qh + (m_base + mf * 16 + r0) * 128 + kk);
#pragma unroll
      for (int nf = 0; nf < 4; ++nf) {
        const int d2 = wid * 64 + nf * 16 + r0;
        bf16x8 b = *(const bf16x8*)(kvsTh + d2 * 128 + kk);
#pragma unroll
        for (int mf = 0; mf < 2; ++mf) acc[mf][nf] = mfma_bf16(a[mf], b, acc[mf][nf]);
      }
    }
#pragma unroll
    for (int mf = 0; mf < 2; ++mf)
#pragma unroll
      for (int nf = 0; nf < 4; ++nf)
#pragma unroll
        for (int r = 0; r < 4; ++r) {
          const int s = m_base + mf * 16 + rr + r;
          const int d2 = wid * 64 + nf * 16 + r0;
          const float y = acc[mf][nf][r];
          const float u = 0.7978845608028654f * (y + 0.044715f * y * y * y);
          out[(size_t)s * 4096 + h * 128 + d2] = 0.5f * y * (1.f + tanhf(u));
        }
  } else {
    const int b2 = bid - 128;
    const int h = b2 >> 2, w = b2 & 3;
    const int m_base = w * 32;
    const __bf16* kTh = kdT + (size_t)h * 16384;
    const __bf16* vTh = vT + (size_t)h * 16384;

    f32x4 acc[2][4];
#pragma unroll
    for (int mf = 0; mf < 2; ++mf)
#pragma unroll
      for (int nf = 0; nf < 4; ++nf) acc[mf][nf] = (f32x4){0.f, 0.f, 0.f, 0.f};
#pragma unroll
    for (int k0 = 0; k0 < 128; k0 += 32) {
      const int kk = k0 + g8;
      bf16x8 a[2];
#pragma unroll
      for (int mf = 0; mf < 2; ++mf)
        a[mf] = *(const bf16x8*)(kTh + (m_base + mf * 16 + r0) * 128 + kk);
#pragma unroll
      for (int nf = 0; nf < 4; ++nf) {
        const int j = wid * 64 + nf * 16 + r0;
        bf16x8 b = *(const bf16x8*)(vTh + j * 128 + kk);
#pragma unroll
        for (int mf = 0; mf < 2; ++mf) acc[mf][nf] = mfma_bf16(a[mf], b, acc[mf][nf]);
      }
    }
#pragma unroll
    for (int mf = 0; mf < 2; ++mf)
#pragma unroll
      for (int nf = 0; nf < 4; ++nf)
#pragma unroll
        for (int r = 0; r < 4; ++r) {
          const int i = m_base + mf * 16 + rr + r;
          const int j = wid * 64 + nf * 16 + r0;
          const float dSi = exp2f(128.f * log2f(alpha[h * 128 + i]));
          const float val = acc[mf][nf][r] + kvs[(size_t)h * 16384 + i * 128 + j] * dSi;
          out[524288 + (size_t)h * 16384 + i * 128 + j] = val;
        }
  }
}

extern "C" void kernel_launch(void* const* d_in, const int* in_sizes, int n_in,
                              void* d_out, int out_size, void* d_ws, size_t ws_size,
                              hipStream_t stream) {
  const float* x = (const float*)d_in[0];      // (128, 4096)
  const float* W = (const float*)d_in[1];      // (12288, 4096)
  const float* alpha = (const float*)d_in[2];  // (32, 128)
  const float* kvs = (const float*)d_in[3];    // (32, 128, 128)
  float* out = (float*)d_out;

  char* ws = (char*)d_ws;
  __bf16* xb = (__bf16*)ws;                      // 1 MB
  __bf16* qd = (__bf16*)(ws + (1u << 20));       // 1 MB each
  __bf16* kd = (__bf16*)(ws + 2u * (1u << 20));
  __bf16* kdT = (__bf16*)(ws + 3u * (1u << 20));
  __bf16* vT = (__bf16*)(ws + 4u * (1u << 20));
  __bf16* kvsT = (__bf16*)(ws + 5u * (1u << 20));
  float* P = (float*)(ws + 6u * (1u << 20));     // KS * 6,291,456 B

  const size_t pbytes = ws_size > 6u * (1u << 20) ? ws_size - 6u * (1u << 20) : 0;
  int KS = 1;
  while (KS < 4 && (size_t)(KS * 2) * 6291456ull <= pbytes) KS *= 2;
  const int kc_len = 4096 / KS;

  prep_kernel<<<384, 256, 0, stream>>>(x, xb, kvs, alpha, kvsT);
  gemm_split_kernel<<<192 * KS, 256, 0, stream>>>(xb, W, P, kc_len);
  reduce_kernel<<<384, 256, 0, stream>>>(P, alpha, qd, kd, kdT, vT, KS);
  heads_kernel<<<256, 128, 0, stream>>>(qd, kd, kdT, vT, kvsT, kvs, alpha, out);
}